// Round 1
// 1052.052 us; speedup vs baseline: 1.6642x; 1.6642x over previous
//
#include <hip/hip_runtime.h>

// Problem constants
constexpr int B_ = 4, L_ = 2048, D_ = 512, H_ = 8, C_ = 3, DH_ = 64;
constexpr long long OUT0 = (long long)B_ * L_ * D_;   // out elements; probs follows

typedef short bf16x8 __attribute__((ext_vector_type(8)));
typedef short short4v __attribute__((ext_vector_type(4)));
typedef float floatx4 __attribute__((ext_vector_type(4)));

__device__ __forceinline__ float bf2f(short s) {
    union { unsigned u; float f; } x;
    x.u = ((unsigned)(unsigned short)s) << 16;
    return x.f;
}
__device__ __forceinline__ short f2bf(float f) {
    union { float f; unsigned u; } x; x.f = f;
    unsigned r = x.u + 0x7fff + ((x.u >> 16) & 1);   // round-nearest-even
    return (short)(r >> 16);
}
// dtype-adaptive scalar load
__device__ __forceinline__ float ld1(const void* p, long long i, int f32) {
    return f32 ? ((const float*)p)[i] : bf2f(((const short*)p)[i]);
}
// 8-element load -> bf16x8. f32 path uses 2x float4: requires i%4==0 and 16B-aligned base.
__device__ __forceinline__ bf16x8 ld8(const void* p, long long i, int f32) {
    bf16x8 r;
    if (f32) {
        const float4* q = (const float4*)((const float*)p + i);
        float4 a = q[0], b = q[1];
        r[0] = f2bf(a.x); r[1] = f2bf(a.y); r[2] = f2bf(a.z); r[3] = f2bf(a.w);
        r[4] = f2bf(b.x); r[5] = f2bf(b.y); r[6] = f2bf(b.z); r[7] = f2bf(b.w);
    } else {
        r = *(const bf16x8*)((const short*)p + i);
    }
    return r;
}
// 8-element load -> float[8]. Same alignment requirement as ld8 in f32 mode.
__device__ __forceinline__ void ldf8(const void* p, long long i, int f32, float* o) {
    if (f32) {
        const float4* q = (const float4*)((const float*)p + i);
        float4 a = q[0], b = q[1];
        o[0] = a.x; o[1] = a.y; o[2] = a.z; o[3] = a.w;
        o[4] = b.x; o[5] = b.y; o[6] = b.z; o[7] = b.w;
    } else {
        bf16x8 v = *(const bf16x8*)((const short*)p + i);
#pragma unroll
        for (int j = 0; j < 8; ++j) o[j] = bf2f(v[j]);
    }
}
// force a (known-uniform) value into an SGPR
__device__ __forceinline__ float rf(float x) {
    union { float f; int i; } u; u.f = x;
    u.i = __builtin_amdgcn_readfirstlane(u.i);
    return u.f;
}

// ---------------------------------------------------------------------------
// Kernel 0: dtype sniffer (unchanged). flag = 1 -> buffers are float32.
// ---------------------------------------------------------------------------
__global__ void sniff_dtype(const void* q, int* flag) {
    __shared__ int bad;
    if (threadIdx.x == 0) bad = 0;
    __syncthreads();
    const short* s = (const short*)q;
    int tbad = 0;
    for (int i = threadIdx.x; i < 4096; i += 256) {
        float v = bf2f(s[i]);
        if (!(fabsf(v) < 1e4f)) tbad = 1;   // catches NaN too
    }
    if (tbad) atomicOr(&bad, 1);
    __syncthreads();
    if (threadIdx.x == 0) *flag = bad ? 1 : 0;
}

// ---------------------------------------------------------------------------
// Kernel 1: qa8[(b*L+i)*8+h] = q[b,i,:].Wq[:,h]+bq[h]; same for k -> ka8.
// One wave per row; lanes split D; W rows loaded as 2x float4 per lane.
// Layout change vs old version: h contiguous (so attn_probs can float4-load ka).
// ---------------------------------------------------------------------------
__global__ __launch_bounds__(256) void proj_qk(
    const void* __restrict__ q, const void* __restrict__ k,
    const void* __restrict__ Wq, const void* __restrict__ bq,
    const void* __restrict__ Wk, const void* __restrict__ bk,
    float* __restrict__ qa8, float* __restrict__ ka8, const int* __restrict__ flagp)
{
    const int f32 = *flagp;
    int gtid = blockIdx.x * 256 + threadIdx.x;
    int row  = gtid >> 6;          // 0 .. B*L-1
    int lane = gtid & 63;
    long long rbase = (long long)row * D_;
    float aq[8] = {0,0,0,0,0,0,0,0}, ak[8] = {0,0,0,0,0,0,0,0};
    for (int d0 = 0; d0 < D_; d0 += 64) {
        int d = d0 + lane;
        float qv = ld1(q, rbase + d, f32);
        float kv = ld1(k, rbase + d, f32);
        float wq[8], wk[8];
        ldf8(Wq, (long long)d * H_, f32, wq);
        ldf8(Wk, (long long)d * H_, f32, wk);
#pragma unroll
        for (int h = 0; h < 8; h++) { aq[h] += qv * wq[h]; ak[h] += kv * wk[h]; }
    }
#pragma unroll
    for (int h = 0; h < 8; h++) {
#pragma unroll
        for (int st = 32; st >= 1; st >>= 1) {
            aq[h] += __shfl_xor(aq[h], st, 64);
            ak[h] += __shfl_xor(ak[h], st, 64);
        }
    }
    if (lane == 0) {
#pragma unroll
        for (int h = 0; h < 8; h++) {
            qa8[(long long)row * 8 + h] = aq[h] + ld1(bq, h, f32);
            ka8[(long long)row * 8 + h] = ak[h] + ld1(bk, h, f32);
        }
    }
}

// ---------------------------------------------------------------------------
// Kernel 1b: pack dkt/dkb/dks into pkd[b*L+j][12] (f32) so attn_probs can
// read all per-j features with 3 float4 loads. Layout:
//   [kt0,kt1,kt2, kb0,kb1,kb2, s00,s01,s02, s10,s11,s12]
// ---------------------------------------------------------------------------
__global__ __launch_bounds__(256) void pack_dk(
    const void* __restrict__ dkt, const void* __restrict__ dkb,
    const void* __restrict__ dks, float* __restrict__ pkd,
    const int* __restrict__ flagp)
{
    const int f32 = *flagp;
    int j = blockIdx.x * 256 + threadIdx.x;   // 0 .. B*L-1 (grid exact)
    long long tb = (long long)j * 3, sb = (long long)j * 6;
    float o[12];
#pragma unroll
    for (int c = 0; c < 3; ++c) {
        o[c]     = ld1(dkt, tb + c, f32);
        o[3 + c] = ld1(dkb, tb + c, f32);
    }
#pragma unroll
    for (int c = 0; c < 6; ++c) o[6 + c] = ld1(dks, sb + c, f32);
    float4* op = (float4*)(pkd + (long long)j * 12);
    float4 a, b, c;
    a.x = o[0]; a.y = o[1]; a.z = o[2];  a.w = o[3];
    b.x = o[4]; b.y = o[5]; b.z = o[6];  b.w = o[7];
    c.x = o[8]; c.y = o[9]; c.z = o[10]; c.w = o[11];
    op[0] = a; op[1] = b; op[2] = c;
}

// ---------------------------------------------------------------------------
// Generic batched MFMA bf16 GEMM: C = A(MxK) @ B(KxN) (+bias), 64x64 tiles.
// New vs previous round:
//  - B staging vectorized: row-major B loaded 8-wide per thread + LDS
//    transpose scatter; bT=1 means B is stored [n][k] (pre-transposed) and
//    stages with a single bf16x8 load.
//  - f32 A/B loads use float4 pairs (alignment guaranteed by call sites).
//  - cT=1 writes C transposed (C[col*ldc+row]) with 8B/16B vector stores.
// Fragment layouts as verified previously:
//   A-frag A[m=lane&15][k=quad*8+j]; Bs holds B^T[n][k]; D[row=quad*4+r][col=lane&15].
// ---------------------------------------------------------------------------
__global__ __launch_bounds__(256) void gemm_bf16(
    const void* __restrict__ A, long long aOff, int lda, long long sAb, long long sAh, int aMode,
    const void* __restrict__ Bm, long long bOff, int ldb, long long sBb, long long sBh, int bMode, int bT,
    const void* __restrict__ bias, int biasMode,
    void* __restrict__ C, long long cOff, int ldc, long long sCb, long long sCh, int cMode, int cT,
    int K, int nbh, const int* __restrict__ flagp)
{
    __shared__ __align__(16) short As[64][40];
    __shared__ __align__(16) short Bs[64][40];
    const int f = *flagp;
    const int fa = (aMode == 2) ? f : aMode;
    const int fb = (bMode == 2) ? f : bMode;
    const int fbias = (biasMode == 2) ? f : biasMode;
    const int fc = (cMode == 2) ? f : cMode;

    int z = blockIdx.z;
    int zb = z / nbh, zh = z % nbh;
    long long abase = aOff + (long long)zb * sAb + (long long)zh * sAh;
    long long bbase = bOff + (long long)zb * sBb + (long long)zh * sBh;
    long long cbase = cOff + (long long)zb * sCb + (long long)zh * sCh;

    int m0 = blockIdx.x * 64, n0 = blockIdx.y * 64;
    int tid = threadIdx.x;
    int lane = tid & 63, wave = tid >> 6;
    int wm = (wave & 1) * 32, wn = (wave >> 1) * 32;
    int qd = lane >> 4, ln = lane & 15;

    int arow = tid >> 2, acol = (tid & 3) * 8;   // A stage: 64 rows x 32 k

    floatx4 acc[2][2] = {};

    for (int k0 = 0; k0 < K; k0 += 32) {
        bf16x8 av = ld8(A, abase + (long long)(m0 + arow) * lda + k0 + acol, fa);
        bf16x8 bv;
        if (bT) bv = ld8(Bm, bbase + (long long)(n0 + (tid >> 2)) * ldb + k0 + (tid & 3) * 8, fb);
        else    bv = ld8(Bm, bbase + (long long)(k0 + (tid >> 3)) * ldb + n0 + (tid & 7) * 8, fb);
        __syncthreads();
        *(bf16x8*)&As[arow][acol] = av;
        if (bT) {
            *(bf16x8*)&Bs[tid >> 2][(tid & 3) * 8] = bv;      // already [n][k]
        } else {
#pragma unroll
            for (int jj = 0; jj < 8; ++jj) Bs[(tid & 7) * 8 + jj][tid >> 3] = bv[jj];
        }
        __syncthreads();
        bf16x8 a0 = *(const bf16x8*)&As[wm + ln][qd * 8];
        bf16x8 a1 = *(const bf16x8*)&As[wm + 16 + ln][qd * 8];
        bf16x8 b0 = *(const bf16x8*)&Bs[wn + ln][qd * 8];
        bf16x8 b1 = *(const bf16x8*)&Bs[wn + 16 + ln][qd * 8];
        acc[0][0] = __builtin_amdgcn_mfma_f32_16x16x32_bf16(a0, b0, acc[0][0], 0, 0, 0);
        acc[0][1] = __builtin_amdgcn_mfma_f32_16x16x32_bf16(a0, b1, acc[0][1], 0, 0, 0);
        acc[1][0] = __builtin_amdgcn_mfma_f32_16x16x32_bf16(a1, b0, acc[1][0], 0, 0, 0);
        acc[1][1] = __builtin_amdgcn_mfma_f32_16x16x32_bf16(a1, b1, acc[1][1], 0, 0, 0);
    }

#pragma unroll
    for (int ti = 0; ti < 2; ti++) {
#pragma unroll
        for (int tj = 0; tj < 2; tj++) {
            int col = n0 + wn + tj * 16 + ln;
            float bc = bias ? ld1(bias, col, fbias) : 0.f;
            if (!cT) {
#pragma unroll
                for (int r = 0; r < 4; r++) {
                    int row = m0 + wm + ti * 16 + qd * 4 + r;
                    float val = acc[ti][tj][r] + bc;
                    long long ci = cbase + (long long)row * ldc + col;
                    if (fc) ((float*)C)[ci] = val;
                    else    ((short*)C)[ci] = f2bf(val);
                }
            } else {
                int row0 = m0 + wm + ti * 16 + qd * 4;        // 4 consecutive rows
                long long ci = cbase + (long long)col * ldc + row0;
                if (fc) {
                    float4 v;
                    v.x = acc[ti][tj][0] + bc; v.y = acc[ti][tj][1] + bc;
                    v.z = acc[ti][tj][2] + bc; v.w = acc[ti][tj][3] + bc;
                    *(float4*)((float*)C + ci) = v;
                } else {
                    short4v v;
#pragma unroll
                    for (int r = 0; r < 4; r++) v[r] = f2bf(acc[ti][tj][r] + bc);
                    *(short4v*)((short*)C + ci) = v;
                }
            }
        }
    }
}

// ---------------------------------------------------------------------------
// Kernel 3: scores -> softmax -> probs, restructured.
//  - 256 threads = 4 waves; each wave owns 2 full rows (i), lanes split j.
//  - Online softmax (1 exp/elem via exp(-|s-m|) + select) in pass 1,
//    recompute + normalized store in pass 2. No LDS, no __syncthreads.
//  - All wave-uniform values (weights, dq, qa) forced to SGPRs (rf).
//  - Side inputs pre-packed: pkd (3x float4/j), ka8 (2x float4/j).
// Target: VGPR <= 128 (launch_bounds 256,4) -> 16 waves/CU.
// ---------------------------------------------------------------------------
__device__ __forceinline__ float score_eval(
    float f0, float f1, float f2, float kah, float qah,
    float ww0, float ww1, float ww2, float bwh,
    float wb0, float wb1, float wb2, float bbh)
{
    float gw = bwh + f0 * ww0 + f1 * ww1 + f2 * ww2;
    float sp = (gw > 15.f) ? gw : __logf(1.f + __expf(gw));
    float gb = bbh + f0 * wb0 + f1 * wb1 + f2 * wb2;
    return qah * kah * sp + gb;
}

__device__ __forceinline__ void load_jpair(
    const float* __restrict__ pkb, const float* __restrict__ kab, int j0,
    float pk[2][12], float ka[2][8])
{
#pragma unroll
    for (int jj = 0; jj < 2; ++jj) {
        const float4* pp = (const float4*)(pkb + (long long)(j0 + jj) * 12);
        float4 x = pp[0], y = pp[1], z = pp[2];
        pk[jj][0] = x.x; pk[jj][1] = x.y; pk[jj][2]  = x.z; pk[jj][3]  = x.w;
        pk[jj][4] = y.x; pk[jj][5] = y.y; pk[jj][6]  = y.z; pk[jj][7]  = y.w;
        pk[jj][8] = z.x; pk[jj][9] = z.y; pk[jj][10] = z.z; pk[jj][11] = z.w;
        const float4* kp = (const float4*)(kab + (long long)(j0 + jj) * 8);
        float4 u = kp[0], w = kp[1];
        ka[jj][0] = u.x; ka[jj][1] = u.y; ka[jj][2] = u.z; ka[jj][3] = u.w;
        ka[jj][4] = w.x; ka[jj][5] = w.y; ka[jj][6] = w.z; ka[jj][7] = w.w;
    }
}

__global__ __launch_bounds__(256, 4) void attn_probs(
    const void* __restrict__ dq_g,
    const float* __restrict__ pkd,
    const float* __restrict__ qa8,
    const float* __restrict__ ka8,
    const void* __restrict__ Ww_g, const void* __restrict__ bw_g,
    const void* __restrict__ Wb_g, const void* __restrict__ bb_g,
    void* __restrict__ d_out, const int* __restrict__ flagp)
{
    const int f32 = *flagp;
    const int blk = blockIdx.x;                      // B * L/8 = 1024
    const int b = blk >> 8;                          // L/8 = 256 i-blocks per b
    const int i0 = (blk & 255) * 8 + (threadIdx.x >> 6) * 2;
    const int lane = threadIdx.x & 63;

    // wave-uniform weights -> SGPRs
    float ww[3][8], wbm[3][8], bwv[8], bbv[8];
#pragma unroll
    for (int h = 0; h < 8; ++h) {
#pragma unroll
        for (int c = 0; c < 3; ++c) {
            ww[c][h]  = rf(ld1(Ww_g, c * H_ + h, f32));
            wbm[c][h] = rf(ld1(Wb_g, c * H_ + h, f32));
        }
        bwv[h] = rf(ld1(bw_g, h, f32));
        bbv[h] = rf(ld1(bb_g, h, f32));
    }
    float dq0[2][3], qav[2][8];
#pragma unroll
    for (int ii = 0; ii < 2; ++ii) {
        long long r = (long long)b * L_ + (i0 + ii);
#pragma unroll
        for (int c = 0; c < 3; ++c) dq0[ii][c] = rf(ld1(dq_g, r * C_ + c, f32));
#pragma unroll
        for (int h = 0; h < 8; ++h) qav[ii][h] = rf(qa8[r * 8 + h]);
    }

    const float* pkb = pkd + (long long)b * L_ * 12;
    const float* kab = ka8 + (long long)b * L_ * 8;

    float m[2][8], ssum[2][8];
#pragma unroll
    for (int ii = 0; ii < 2; ++ii)
#pragma unroll
        for (int h = 0; h < 8; ++h) { m[ii][h] = -1e30f; ssum[ii][h] = 0.f; }

    // ---- pass 1: online max+sum over all j -------------------------------
#pragma unroll 1
    for (int it = 0; it < 16; ++it) {
        int j0 = it * 128 + lane * 2;
        float pk[2][12], ka[2][8];
        load_jpair(pkb, kab, j0, pk, ka);
#pragma unroll
        for (int jj = 0; jj < 2; ++jj) {
            float fv[2][3];
#pragma unroll
            for (int ii = 0; ii < 2; ++ii)
#pragma unroll
                for (int c = 0; c < 3; ++c)
                    fv[ii][c] = fabsf(dq0[ii][c] - pk[jj][c]) * pk[jj][6 + c]
                              + fabsf(dq0[ii][c] - pk[jj][3 + c]) * pk[jj][9 + c];
#pragma unroll
            for (int ii = 0; ii < 2; ++ii)
#pragma unroll
                for (int h = 0; h < 8; ++h) {
                    float s = score_eval(fv[ii][0], fv[ii][1], fv[ii][2], ka[jj][h], qav[ii][h],
                                         ww[0][h], ww[1][h], ww[2][h], bwv[h],
                                         wbm[0][h], wbm[1][h], wbm[2][h], bbv[h]);
                    float mo = m[ii][h];
                    float t  = __expf(-fabsf(s - mo));   // = exp(min(s,mo)-max(s,mo))
                    bool g = s > mo;
                    ssum[ii][h] = g ? (ssum[ii][h] * t + 1.f) : (ssum[ii][h] + t);
                    m[ii][h]    = g ? s : mo;
                }
        }
    }

    // ---- wave reduce (lanes all hold partial (m, ssum) for same rows) ----
#pragma unroll
    for (int ii = 0; ii < 2; ++ii)
#pragma unroll
        for (int h = 0; h < 8; ++h) {
            float mm = m[ii][h], ss = ssum[ii][h];
#pragma unroll
            for (int st = 32; st >= 1; st >>= 1) {
                float mo = __shfl_xor(mm, st, 64);
                float so = __shfl_xor(ss, st, 64);
                float mn = fmaxf(mm, mo);
                ss = ss * __expf(mm - mn) + so * __expf(mo - mn);
                mm = mn;
            }
            m[ii][h] = mm;
            ssum[ii][h] = 1.f / ss;     // now holds 1/sum
        }

    // ---- pass 2: recompute scores, write normalized probs ----------------
#pragma unroll 1
    for (int it = 0; it < 16; ++it) {
        int j0 = it * 128 + lane * 2;
        float pk[2][12], ka[2][8];
        load_jpair(pkb, kab, j0, pk, ka);
        float fv[2][2][3];   // [jj][ii][c]
#pragma unroll
        for (int jj = 0; jj < 2; ++jj)
#pragma unroll
            for (int ii = 0; ii < 2; ++ii)
#pragma unroll
                for (int c = 0; c < 3; ++c)
                    fv[jj][ii][c] = fabsf(dq0[ii][c] - pk[jj][c]) * pk[jj][6 + c]
                                  + fabsf(dq0[ii][c] - pk[jj][3 + c]) * pk[jj][9 + c];
#pragma unroll
        for (int ii = 0; ii < 2; ++ii)
#pragma unroll
            for (int h = 0; h < 8; ++h) {
                float s0 = score_eval(fv[0][ii][0], fv[0][ii][1], fv[0][ii][2], ka[0][h], qav[ii][h],
                                      ww[0][h], ww[1][h], ww[2][h], bwv[h],
                                      wbm[0][h], wbm[1][h], wbm[2][h], bbv[h]);
                float s1 = score_eval(fv[1][ii][0], fv[1][ii][1], fv[1][ii][2], ka[1][h], qav[ii][h],
                                      ww[0][h], ww[1][h], ww[2][h], bwv[h],
                                      wbm[0][h], wbm[1][h], wbm[2][h], bbv[h]);
                float p0 = __expf(s0 - m[ii][h]) * ssum[ii][h];
                float p1 = __expf(s1 - m[ii][h]) * ssum[ii][h];
                long long idx = ((long long)(b * H_ + h) * L_ + (i0 + ii)) * L_ + j0;
                if (f32) {
                    float2 v; v.x = p0; v.y = p1;
                    *(float2*)((float*)d_out + OUT0 + idx) = v;
                } else {
                    unsigned pkk = (unsigned)(unsigned short)f2bf(p0)
                                 | ((unsigned)(unsigned short)f2bf(p1) << 16);
                    *(unsigned*)((short*)d_out + OUT0 + idx) = pkk;
                }
            }
    }
}

// ---------------------------------------------------------------------------
extern "C" void kernel_launch(void* const* d_in, const int* in_sizes, int n_in,
                              void* d_out, int out_size, void* d_ws, size_t ws_size,
                              hipStream_t stream)
{
    const void* q   = d_in[0];
    const void* k   = d_in[1];
    const void* v   = d_in[2];
    const void* dq  = d_in[3];
    const void* dkt = d_in[4];
    const void* dkb = d_in[5];
    const void* dks = d_in[6];
    const void* Wq  = d_in[7];
    const void* bq  = d_in[8];
    const void* Wk  = d_in[9];
    const void* bk  = d_in[10];
    // d_in[11] Wc, d_in[12] bc: unused by the reference
    const void* Wv  = d_in[13];
    const void* bv  = d_in[14];
    const void* Wo  = d_in[15];
    const void* bo  = d_in[16];
    const void* Ww  = d_in[17];
    const void* bw  = d_in[18];
    const void* Wb  = d_in[19];
    const void* bb  = d_in[20];

    // workspace layout (~16.8 MB total, <= previous session's 17.3 MB footprint):
    //   [0,1024)                     flag
    //   [1024, +8.4MB)               vpt  bf16 [b][h][dh][L]  (v @ Wv, transposed)
    //   X = 1024+8.4MB, [X, +8.4MB)  region shared in time:
    //       steps 1-3: qa8 (256KB) | ka8 (256KB) | pkd (384KB)
    //       steps 4-5: attn bf16 [B*L][D]   (qa8/ka8/pkd dead by then)
    int*   flag = (int*)d_ws;
    short* vpt  = (short*)((char*)d_ws + 1024);
    char*  X    = (char*)d_ws + 1024 + (size_t)B_ * L_ * D_ * 2;
    float* qa8  = (float*)X;
    float* ka8  = qa8 + (size_t)B_ * L_ * H_;
    float* pkd  = ka8 + (size_t)B_ * L_ * H_;
    short* attn = (short*)X;

    // 0. dtype sniff
    sniff_dtype<<<dim3(1), 256, 0, stream>>>(q, flag);

    // 1. qa8 / ka8 projections ([b*L+i][8] layout)
    proj_qk<<<dim3(B_ * L_ * 64 / 256), 256, 0, stream>>>(q, k, Wq, bq, Wk, bk, qa8, ka8, flag);

    // 1b. pack per-j distance features
    pack_dk<<<dim3(B_ * L_ / 256), 256, 0, stream>>>(dkt, dkb, dks, pkd, flag);

    // 2. vpt[b][d][i] = (v[b] @ Wv + bv)^T  (bf16, transposed for fast B-staging)
    gemm_bf16<<<dim3(L_ / 64, D_ / 64, B_), 256, 0, stream>>>(
        v, 0, D_, (long long)L_ * D_, 0, 2,
        Wv, 0, D_, 0, 0, 2, /*bT=*/0,
        bv, 2,
        (void*)vpt, 0, /*ldc=*/L_, (long long)L_ * D_, 0, /*cMode=*/0, /*cT=*/1,
        D_, 1, flag);

    // 3. scores -> softmax -> probs (written into d_out at element OUT0)
    attn_probs<<<dim3(B_ * L_ / 8), 256, 0, stream>>>(
        dq, pkd, qa8, ka8, Ww, bw, Wb, bb, d_out, flag);

    // 4. attn[b,i,h*64+dh] = sum_j probs[b,h,i,j] * vpt[b,h,dh,j]
    gemm_bf16<<<dim3(L_ / 64, 1, B_ * H_), 256, 0, stream>>>(
        d_out, OUT0, L_, (long long)H_ * L_ * L_, (long long)L_ * L_, 2,
        (void*)vpt, 0, L_, (long long)L_ * D_, (long long)DH_ * L_, 0, /*bT=*/1,
        nullptr, 0,
        (void*)attn, 0, D_, (long long)L_ * D_, DH_, 0, /*cT=*/0,
        L_, H_, flag);

    // 5. out = attn @ Wo + bo  (into d_out[0..OUT0), sniffed dtype)
    gemm_bf16<<<dim3(B_ * L_ / 64, D_ / 64, 1), 256, 0, stream>>>(
        attn, 0, D_, 0, 0, 0,
        Wo, 0, D_, 0, 0, 2, /*bT=*/0,
        bo, 2,
        d_out, 0, D_, 0, 0, 2, /*cT=*/0,
        D_, 1, flag);
}